// Round 12
// baseline (194.352 us; speedup 1.0000x reference)
//
#include <hip/hip_runtime.h>
#include <hip/hip_fp16.h>
#include <math.h>

#define N_NODES 50000
#define N_EDGES 600000
#define H 128
#define BN_EPS 1e-5f
#define MAXDEG 48     // max Poisson(12) degree over 50k nodes ~36; P(>=48) ~ 3e-9
#define CNT_STRIDE 16 // kept from R10 (verified config; scatter is atomic-throughput-bound)

typedef unsigned short ushort_t;
typedef unsigned int uint_t;
typedef _Float16 f16x8 __attribute__((ext_vector_type(8)));
typedef float f32x4 __attribute__((ext_vector_type(4)));

// DPP lane-exchange on the VALU pipe (vs __shfl_xor -> ds_swizzle on the LDS pipe).
template <int CTRL>
static __device__ __forceinline__ float dpp_xor_f(float x) {
    int xi = __builtin_bit_cast(int, x);
    int r = __builtin_amdgcn_update_dpp(0, xi, CTRL, 0xF, 0xF, true);
    return __builtin_bit_cast(float, r);
}
#define DPP_XOR1 0xB1   // quad_perm[1,0,3,2]
#define DPP_XOR2 0x4E   // quad_perm[2,3,0,1]
#define DPP_XOR8 0x128  // row_ror:8 ((i+8)%16 == i^8 within a 16-lane row)

#define WT_STRIDE 136   // halfs per Wt row (128 + 8 pad -> 2-way LDS bank alias = free)

// ---------------- K1: bucket scatter + emb->fp16 + W->transposed fp16 (Wt[j][k]) ----------------
// Scatter is at its atomic-throughput floor (R9 ILP null, R10 line-pad null). ushort
// slots halve random-write line traffic (verified R7). Wt packing feeds the MFMA
// matmul: Wt[j][k] = W[k][j], fp16, padded stride 136.
__global__ void k_scatter(const int* __restrict__ src, const int* __restrict__ dst,
                          int* __restrict__ cnt, ushort_t* __restrict__ slots,
                          const float* __restrict__ emb, __half* __restrict__ emb16,
                          const float* __restrict__ W, __half* __restrict__ wt) {
    int i = blockIdx.x * blockDim.x + threadIdx.x;
    int e0 = i * 4;
    if (e0 < N_EDGES) {                   // 600000 % 4 == 0 -> no tail
        int4 s4 = *(const int4*)(src + e0);
        int4 d4 = *(const int4*)(dst + e0);
        int p0 = atomicAdd(cnt + d4.x * CNT_STRIDE, 1);
        int p1 = atomicAdd(cnt + d4.y * CNT_STRIDE, 1);
        int p2 = atomicAdd(cnt + d4.z * CNT_STRIDE, 1);
        int p3 = atomicAdd(cnt + d4.w * CNT_STRIDE, 1);
        if (p0 < MAXDEG) slots[d4.x * MAXDEG + p0] = (ushort_t)s4.x;
        if (p1 < MAXDEG) slots[d4.y * MAXDEG + p1] = (ushort_t)s4.y;
        if (p2 < MAXDEG) slots[d4.z * MAXDEG + p2] = (ushort_t)s4.z;
        if (p3 < MAXDEG) slots[d4.w * MAXDEG + p3] = (ushort_t)s4.w;
    }
    if (i < N_NODES * H / 8) {
        float4 f0 = ((const float4*)emb)[2 * i];
        float4 f1 = ((const float4*)emb)[2 * i + 1];
        union { uint4 u; __half2 h2[4]; } U;
        U.h2[0] = __floats2half2_rn(f0.x, f0.y);
        U.h2[1] = __floats2half2_rn(f0.z, f0.w);
        U.h2[2] = __floats2half2_rn(f1.x, f1.y);
        U.h2[3] = __floats2half2_rn(f1.z, f1.w);
        ((uint4*)emb16)[i] = U.u;
    }
    if (i < H * H / 8) {                  // 2048 threads: Wt[j][kc..kc+8)
        int j  = i >> 4;                  // 0..127 (output column)
        int kc = (i & 15) * 8;            // 0..120
        union { uint4 u; __half2 h2[4]; } U;
#pragma unroll
        for (int q = 0; q < 4; ++q) {
            float lo = W[(size_t)(kc + 2 * q) * H + j];
            float hi = W[(size_t)(kc + 2 * q + 1) * H + j];
            U.h2[q] = __floats2half2_rn(lo, hi);
        }
        *(uint4*)(wt + (size_t)j * WT_STRIDE + kc) = U.u;
    }
}

#define F4SCALE(a, s) { (a).x *= (s); (a).y *= (s); (a).z *= (s); (a).w *= (s); }
#define F4FMA(a, e, v) { (a).x += (e)*(v).x; (a).y += (e)*(v).y; (a).z += (e)*(v).z; (a).w += (e)*(v).w; }
#define F4DPPADD8(a) { (a).x += dpp_xor_f<DPP_XOR8>((a).x); (a).y += dpp_xor_f<DPP_XOR8>((a).y); \
                       (a).z += dpp_xor_f<DPP_XOR8>((a).z); (a).w += dpp_xor_f<DPP_XOR8>((a).w); }
#define F4SHFLADD(a, msk) { (a).x += __shfl_xor((a).x, msk, 64); (a).y += __shfl_xor((a).y, msk, 64); \
                            (a).z += __shfl_xor((a).z, msk, 64); (a).w += __shfl_xor((a).w, msk, 64); }
// cvt 16 packed halves (2 x uint4) -> 4 x float4
#define CVT16(pA, pB, o0, o1, o2, o3) { \
    const __half2* _h0 = (const __half2*)&(pA); \
    const __half2* _h1 = (const __half2*)&(pB); \
    float2 _t0 = __half22float2(_h0[0]), _t1 = __half22float2(_h0[1]); \
    float2 _t2 = __half22float2(_h0[2]), _t3 = __half22float2(_h0[3]); \
    float2 _t4 = __half22float2(_h1[0]), _t5 = __half22float2(_h1[1]); \
    float2 _t6 = __half22float2(_h1[2]), _t7 = __half22float2(_h1[3]); \
    o0 = make_float4(_t0.x, _t0.y, _t1.x, _t1.y); \
    o1 = make_float4(_t2.x, _t2.y, _t3.x, _t3.y); \
    o2 = make_float4(_t4.x, _t4.y, _t5.x, _t5.y); \
    o3 = make_float4(_t6.x, _t6.y, _t7.x, _t7.y); }

// ---------------- K2 v8: fused score + online softmax + aggregation (16-edge chunks) ----------------
// one wave per dst node; 8 groups x 8 lanes; lane owns 16 feats. v8 widens the chunk
// to 16 edges: both 8-edge gathers issue back-to-back (2x MLP), ONE combined
// max-reduce + rescale per 16 edges, and 84% of nodes (deg<=16) run a single serial
// phase instead of two. Differs from R2's failed prefetch (branchy copy-forward,
// per-lane conditionals): here the second half is one wave-uniform have2 branch.
// Numerics: only online-max grouping changes — reorder noise ~1e-7 << fp16 quantum.
// b row stays FP32 (R8: b-quant absmax 0.0205 > 0.02, banned).
__global__ __launch_bounds__(256) void k_fused(const float* __restrict__ emb,
                                               const __half* __restrict__ emb16,
                                               const int* __restrict__ cnt,
                                               const ushort_t* __restrict__ slots,
                                               __half* __restrict__ neigh) {
    int wid = (blockIdx.x * blockDim.x + threadIdx.x) >> 6;
    int lane = threadIdx.x & 63;
    if (wid >= N_NODES) return;
    int g = lane >> 3;   // edge slot within chunk-half
    int l = lane & 7;    // feature slice: [16l, 16l+16)

    int deg = min(cnt[wid * CNT_STRIDE], MAXDEG);
    int sid = slots[wid * MAXDEG + min(lane, MAXDEG - 1)];

    const float4* rd = (const float4*)(emb + (size_t)wid * H) + l * 4;
    float4 b0 = rd[0], b1 = rd[1], b2 = rd[2], b3 = rd[3];

    float m = -INFINITY, ssum = 0.0f;
    float4 acc0 = {0,0,0,0}, acc1 = {0,0,0,0}, acc2 = {0,0,0,0}, acc3 = {0,0,0,0};

    for (int cb = 0; cb < deg; cb += 16) {
        int e1 = cb + g;
        bool val1 = e1 < deg;
        bool have2 = (cb + 8) < deg;           // wave-uniform
        int s1 = __shfl(sid, val1 ? e1 : 0, 64);
        const uint4* rs1 = (const uint4*)(emb16 + (size_t)s1 * H) + l * 2;
        uint4 p0 = rs1[0], p1 = rs1[1];        // edge-1: 16 halfs
        uint4 p2 = {}, p3 = {};
        if (have2) {                           // issue second gather immediately (MLP)
            int e2 = cb + 8 + g;
            bool val2 = e2 < deg;
            int s2 = __shfl(sid, val2 ? e2 : 0, 64);
            const uint4* rs2 = (const uint4*)(emb16 + (size_t)s2 * H) + l * 2;
            p2 = rs2[0]; p3 = rs2[1];
        }

        // edge-1: cvt + fp32 dot + feature-slice reduce (xor1/2 DPP, xor4 LDS)
        float4 a0, a1, a2, a3;
        CVT16(p0, p1, a0, a1, a2, a3);
        float v1 = a0.x*b0.x + a0.y*b0.y + a0.z*b0.z + a0.w*b0.w
                 + a1.x*b1.x + a1.y*b1.y + a1.z*b1.z + a1.w*b1.w
                 + a2.x*b2.x + a2.y*b2.y + a2.z*b2.z + a2.w*b2.w
                 + a3.x*b3.x + a3.y*b3.y + a3.z*b3.z + a3.w*b3.w;
        v1 += dpp_xor_f<DPP_XOR1>(v1);
        v1 += dpp_xor_f<DPP_XOR2>(v1);
        v1 += __shfl_xor(v1, 4, 64);
        if (!val1) v1 = -INFINITY;

        float v2 = -INFINITY;
        float4 c0, c1, c2, c3;
        if (have2) {
            CVT16(p2, p3, c0, c1, c2, c3);
            v2 = c0.x*b0.x + c0.y*b0.y + c0.z*b0.z + c0.w*b0.w
               + c1.x*b1.x + c1.y*b1.y + c1.z*b1.z + c1.w*b1.w
               + c2.x*b2.x + c2.y*b2.y + c2.z*b2.z + c2.w*b2.w
               + c3.x*b3.x + c3.y*b3.y + c3.z*b3.z + c3.w*b3.w;
            v2 += dpp_xor_f<DPP_XOR1>(v2);
            v2 += dpp_xor_f<DPP_XOR2>(v2);
            v2 += __shfl_xor(v2, 4, 64);
            if (!((cb + 8 + g) < deg)) v2 = -INFINITY;
        }

        // ONE combined max-reduce + rescale for all 16 edges
        float cm = fmaxf(v1, v2);
        cm = fmaxf(cm, dpp_xor_f<DPP_XOR8>(cm));
        cm = fmaxf(cm, __shfl_xor(cm, 16, 64));
        cm = fmaxf(cm, __shfl_xor(cm, 32, 64));
        float mnew = fmaxf(m, cm);             // slot 0 always valid -> finite
        if (mnew > m) {                        // wave-uniform; skip is bit-identical
            float scale = __expf(m - mnew);    // first chunk: exp(-inf)=0
            ssum *= scale;
            F4SCALE(acc0, scale); F4SCALE(acc1, scale);
            F4SCALE(acc2, scale); F4SCALE(acc3, scale);
            m = mnew;
        }

        float ev1 = __expf(v1 - m);            // invalid: exp(-inf)=0
        ssum += ev1;
        F4FMA(acc0, ev1, a0); F4FMA(acc1, ev1, a1);
        F4FMA(acc2, ev1, a2); F4FMA(acc3, ev1, a3);
        if (have2) {
            float ev2 = __expf(v2 - m);
            ssum += ev2;
            F4FMA(acc0, ev2, c0); F4FMA(acc1, ev2, c1);
            F4FMA(acc2, ev2, c2); F4FMA(acc3, ev2, c3);
        }
    }

    // reduce across the 8 groups: xor8 via DPP (VALU), xor16/32 via LDS
    ssum += dpp_xor_f<DPP_XOR8>(ssum);
    ssum += __shfl_xor(ssum, 16, 64);
    ssum += __shfl_xor(ssum, 32, 64);
    F4DPPADD8(acc0);     F4DPPADD8(acc1);     F4DPPADD8(acc2);     F4DPPADD8(acc3);
    F4SHFLADD(acc0, 16); F4SHFLADD(acc1, 16); F4SHFLADD(acc2, 16); F4SHFLADD(acc3, 16);
    F4SHFLADD(acc0, 32); F4SHFLADD(acc1, 32); F4SHFLADD(acc2, 32); F4SHFLADD(acc3, 32);

    float inv = (deg > 0) ? 1.0f / ssum : 0.0f;
    if (g == 0) {
        F4SCALE(acc0, inv); F4SCALE(acc1, inv); F4SCALE(acc2, inv); F4SCALE(acc3, inv);
        union { uint4 u; __half2 h2[4]; } U0, U1;
        U0.h2[0] = __floats2half2_rn(acc0.x, acc0.y);
        U0.h2[1] = __floats2half2_rn(acc0.z, acc0.w);
        U0.h2[2] = __floats2half2_rn(acc1.x, acc1.y);
        U0.h2[3] = __floats2half2_rn(acc1.z, acc1.w);
        U1.h2[0] = __floats2half2_rn(acc2.x, acc2.y);
        U1.h2[1] = __floats2half2_rn(acc2.z, acc2.w);
        U1.h2[2] = __floats2half2_rn(acc3.x, acc3.y);
        U1.h2[3] = __floats2half2_rn(acc3.z, acc3.w);
        uint4* po = (uint4*)(neigh + (size_t)wid * H);
        po[2 * l] = U0.u;
        po[2 * l + 1] = U1.u;
    }
}

// ---------------- K3 v4: MFMA matmul h = neigh(fp16) @ W(fp16) + fused BN stats (verified R11) ----------------
// mfma_f32_16x16x32_f16, 4 waves/block x 16 rows x 128 cols. C/D col=lane&15,
// row=(lane>>4)*4+reg [m89/m91]; A/B element i at k=(i&3)+16*(i>>2)+(lane>>4)*4.
// B from LDS Wt[j][k] stride 136 (2-way bank alias = free). absmax-verified.
#define MM_ROWS 64
__global__ __launch_bounds__(256, 4) void k_matmul(const __half* __restrict__ neigh,
                                                   const __half* __restrict__ wt,
                                                   __half* __restrict__ hout,
                                                   float* __restrict__ stats) {
    __shared__ __half Wl[H * WT_STRIDE];   // 34816 B; stats scratch aliased after MFMAs
    int t = threadIdx.x;
    int wv = t >> 6;
    int l  = t & 63;
    int r0 = blockIdx.x * MM_ROWS + wv * 16;

    for (int idx = t; idx < H * WT_STRIDE / 8; idx += 256)
        ((uint4*)Wl)[idx] = ((const uint4*)wt)[idx];

    int rowA = r0 + (l & 15);
    if (rowA >= N_NODES) rowA = 0;
    const __half* pa = neigh + (size_t)rowA * H + ((l >> 4) * 4);

    __syncthreads();   // Wl staged

    f32x4 acc[8] = {};
#pragma unroll
    for (int kk = 0; kk < 4; ++kk) {
        uint2 a_lo = *(const uint2*)(pa + kk * 32);
        uint2 a_hi = *(const uint2*)(pa + kk * 32 + 16);
        uint4 au = make_uint4(a_lo.x, a_lo.y, a_hi.x, a_hi.y);
        f16x8 af = __builtin_bit_cast(f16x8, au);
#pragma unroll
        for (int jt = 0; jt < 8; ++jt) {
            const __half* pb = Wl + (size_t)(jt * 16 + (l & 15)) * WT_STRIDE
                             + kk * 32 + ((l >> 4) * 4);
            uint2 b_lo = *(const uint2*)(pb);
            uint2 b_hi = *(const uint2*)(pb + 16);
            uint4 bu = make_uint4(b_lo.x, b_lo.y, b_hi.x, b_hi.y);
            f16x8 bf = __builtin_bit_cast(f16x8, bu);
            acc[jt] = __builtin_amdgcn_mfma_f32_16x16x32_f16(af, bf, acc[jt], 0, 0, 0);
        }
    }

    int rbase = r0 + (l >> 4) * 4;
#pragma unroll
    for (int jt = 0; jt < 8; ++jt) {
        int col = jt * 16 + (l & 15);
#pragma unroll
        for (int reg = 0; reg < 4; ++reg) {
            int row = rbase + reg;
            if (row < N_NODES)
                hout[(size_t)row * H + col] = __float2half(acc[jt][reg]);
        }
    }

    // ---- BN column stats (fp32 from registers), scratch aliased into dead Wl ----
    __syncthreads();                   // all Wl (B) reads done before aliasing
    float* Sl = (float*)Wl;            // 16 x 128 = 8 KB
    float* Ql = Sl + 16 * H;           // next 8 KB
    int srow = wv * 4 + (l >> 4);
#pragma unroll
    for (int jt = 0; jt < 8; ++jt) {
        int col = jt * 16 + (l & 15);
        float s = 0.0f, q = 0.0f;
#pragma unroll
        for (int reg = 0; reg < 4; ++reg) {
            if (rbase + reg < N_NODES) { float v = acc[jt][reg]; s += v; q += v * v; }
        }
        Sl[srow * H + col] = s;
        Ql[srow * H + col] = q;
    }
    __syncthreads();
    if (t < H) {
        float s = 0.0f;
#pragma unroll
        for (int r = 0; r < 16; ++r) s += Sl[r * H + t];
        atomicAdd(stats + t, s);
    } else {
        int j = t - H;
        float q = 0.0f;
#pragma unroll
        for (int r = 0; r < 16; ++r) q += Ql[r * H + j];
        atomicAdd(stats + 128 + j, q);
    }
}

// fast tanh via v_exp: 1 - 2/(exp(2x)+1); saturates correctly at +/-inf
__device__ __forceinline__ float tanh_fast(float x) {
    float e = __expf(2.0f * x);
    return 1.0f - 2.0f / (e + 1.0f);
}

// ---------------- K4: finalize BN (in LDS) + apply + tanh; fp16 h -> fp32 out ----------------
__global__ __launch_bounds__(256) void k_apply_f16(const __half* __restrict__ h,
                                                   float* __restrict__ out,
                                                   const float* __restrict__ stats,
                                                   const float* __restrict__ gamma,
                                                   const float* __restrict__ beta) {
    __shared__ float sc[128], sh[128];
    int t = threadIdx.x;
    if (t < 128) {
        float mean = stats[t] * (1.0f / N_NODES);
        float var = stats[128 + t] * (1.0f / N_NODES) - mean * mean;
        var = fmaxf(var, 0.0f);
        float s = gamma[t] * rsqrtf(var + BN_EPS);
        sc[t] = s;
        sh[t] = beta[t] - mean * s;
    }
    __syncthreads();
    int i = blockIdx.x * 256 + t;                  // 8-half chunk index
    if (i < N_NODES * H / 8) {
        union { uint4 u; __half2 h2[4]; } U;
        U.u = ((const uint4*)h)[i];                // halfs [8i, 8i+8)
        int jb = (i & 15) * 8;                     // column of first half
        float2 f0 = __half22float2(U.h2[0]);
        float2 f1 = __half22float2(U.h2[1]);
        float2 f2 = __half22float2(U.h2[2]);
        float2 f3 = __half22float2(U.h2[3]);
        float4 o0, o1;
        o0.x = tanh_fast(f0.x * sc[jb]     + sh[jb]);
        o0.y = tanh_fast(f0.y * sc[jb + 1] + sh[jb + 1]);
        o0.z = tanh_fast(f1.x * sc[jb + 2] + sh[jb + 2]);
        o0.w = tanh_fast(f1.y * sc[jb + 3] + sh[jb + 3]);
        o1.x = tanh_fast(f2.x * sc[jb + 4] + sh[jb + 4]);
        o1.y = tanh_fast(f2.y * sc[jb + 5] + sh[jb + 5]);
        o1.z = tanh_fast(f3.x * sc[jb + 6] + sh[jb + 6]);
        o1.w = tanh_fast(f3.y * sc[jb + 7] + sh[jb + 7]);
        ((float4*)out)[2 * i]     = o0;
        ((float4*)out)[2 * i + 1] = o1;
    }
}

extern "C" void kernel_launch(void* const* d_in, const int* in_sizes, int n_in,
                              void* d_out, int out_size, void* d_ws, size_t ws_size,
                              hipStream_t stream) {
    const float* emb   = (const float*)d_in[0];
    const float* W     = (const float*)d_in[1];
    const float* gamma = (const float*)d_in[2];
    const float* beta  = (const float*)d_in[3];
    const int*   src   = (const int*)d_in[4];
    const int*   dst   = (const int*)d_in[5];
    float* out = (float*)d_out;

    // workspace: [cnt N*16][stats 256][pad 4][slots16 N*MAXDEG u16]
    //            [neigh16 N*H][hbuf16 N*H][emb16 N*H][wt 128*136 halfs] ~46.5 MB
    int*      cnt   = (int*)d_ws;                                    // N*CNT_STRIDE
    float*    stats = (float*)(cnt + (size_t)N_NODES * CNT_STRIDE);  // 256
    ushort_t* slots = (ushort_t*)((int*)(stats + 256) + 4);          // N*MAXDEG u16
    __half*   neigh = (__half*)(slots + (size_t)N_NODES * MAXDEG);   // N*H fp16
    __half*   hbuf  = neigh + (size_t)N_NODES * H;                   // N*H fp16
    __half*   emb16 = hbuf + (size_t)N_NODES * H;                    // N*H fp16
    __half*   wt    = emb16 + (size_t)N_NODES * H;                   // H*WT_STRIDE halfs

    // one memset zeroes padded cnt + stats + pad (contiguous, async)
    hipMemsetAsync(cnt, 0, ((size_t)N_NODES * CNT_STRIDE + 260) * sizeof(int), stream);
    int nthr_sc = N_NODES * H / 8;                 // 800000 >= 150000 edge-quads
    k_scatter<<<(nthr_sc + 255) / 256, 256, 0, stream>>>(src, dst, cnt, slots, emb, emb16, W, wt);
    k_fused<<<(N_NODES * 64 + 255) / 256, 256, 0, stream>>>(emb, emb16, cnt, slots, neigh);
    int nblk_mm = (N_NODES + MM_ROWS - 1) / MM_ROWS;   // 782
    k_matmul<<<nblk_mm, 256, 0, stream>>>(neigh, wt, hbuf, stats);
    k_apply_f16<<<(N_NODES * H / 8 + 255) / 256, 256, 0, stream>>>(hbuf, out, stats, gamma, beta);
}

// Round 13
// 190.579 us; speedup vs baseline: 1.0198x; 1.0198x over previous
//
#include <hip/hip_runtime.h>
#include <hip/hip_fp16.h>
#include <math.h>

#define N_NODES 50000
#define N_EDGES 600000
#define H 128
#define BN_EPS 1e-5f
#define MAXDEG 48     // max Poisson(12) degree over 50k nodes ~36; P(>=48) ~ 3e-9
#define CNT_STRIDE 16 // kept from R10 (verified config; scatter is atomic-throughput-bound)

typedef unsigned short ushort_t;
typedef unsigned int uint_t;
typedef _Float16 f16x8 __attribute__((ext_vector_type(8)));
typedef float f32x4 __attribute__((ext_vector_type(4)));

// DPP lane-exchange on the VALU pipe (vs __shfl_xor -> ds_swizzle on the LDS pipe).
template <int CTRL>
static __device__ __forceinline__ float dpp_xor_f(float x) {
    int xi = __builtin_bit_cast(int, x);
    int r = __builtin_amdgcn_update_dpp(0, xi, CTRL, 0xF, 0xF, true);
    return __builtin_bit_cast(float, r);
}
#define DPP_XOR1 0xB1   // quad_perm[1,0,3,2]
#define DPP_XOR2 0x4E   // quad_perm[2,3,0,1]
#define DPP_XOR8 0x128  // row_ror:8 ((i+8)%16 == i^8 within a 16-lane row)

#define WT_STRIDE 136   // halfs per Wt row (128 + 8 pad -> 2-way LDS bank alias = free)

// ---------------- K1: bucket scatter + emb->fp16 + W->transposed fp16 (Wt[j][k]) ----------------
// Scatter is at its atomic-throughput floor (R9 ILP null, R10 line-pad null). ushort
// slots halve random-write line traffic (verified R7). Wt packing feeds the MFMA
// matmul: Wt[j][k] = W[k][j], fp16, padded stride 136.
__global__ void k_scatter(const int* __restrict__ src, const int* __restrict__ dst,
                          int* __restrict__ cnt, ushort_t* __restrict__ slots,
                          const float* __restrict__ emb, __half* __restrict__ emb16,
                          const float* __restrict__ W, __half* __restrict__ wt) {
    int i = blockIdx.x * blockDim.x + threadIdx.x;
    int e0 = i * 4;
    if (e0 < N_EDGES) {                   // 600000 % 4 == 0 -> no tail
        int4 s4 = *(const int4*)(src + e0);
        int4 d4 = *(const int4*)(dst + e0);
        int p0 = atomicAdd(cnt + d4.x * CNT_STRIDE, 1);
        int p1 = atomicAdd(cnt + d4.y * CNT_STRIDE, 1);
        int p2 = atomicAdd(cnt + d4.z * CNT_STRIDE, 1);
        int p3 = atomicAdd(cnt + d4.w * CNT_STRIDE, 1);
        if (p0 < MAXDEG) slots[d4.x * MAXDEG + p0] = (ushort_t)s4.x;
        if (p1 < MAXDEG) slots[d4.y * MAXDEG + p1] = (ushort_t)s4.y;
        if (p2 < MAXDEG) slots[d4.z * MAXDEG + p2] = (ushort_t)s4.z;
        if (p3 < MAXDEG) slots[d4.w * MAXDEG + p3] = (ushort_t)s4.w;
    }
    if (i < N_NODES * H / 8) {
        float4 f0 = ((const float4*)emb)[2 * i];
        float4 f1 = ((const float4*)emb)[2 * i + 1];
        union { uint4 u; __half2 h2[4]; } U;
        U.h2[0] = __floats2half2_rn(f0.x, f0.y);
        U.h2[1] = __floats2half2_rn(f0.z, f0.w);
        U.h2[2] = __floats2half2_rn(f1.x, f1.y);
        U.h2[3] = __floats2half2_rn(f1.z, f1.w);
        ((uint4*)emb16)[i] = U.u;
    }
    if (i < H * H / 8) {                  // 2048 threads: Wt[j][kc..kc+8)
        int j  = i >> 4;                  // 0..127 (output column)
        int kc = (i & 15) * 8;            // 0..120
        union { uint4 u; __half2 h2[4]; } U;
#pragma unroll
        for (int q = 0; q < 4; ++q) {
            float lo = W[(size_t)(kc + 2 * q) * H + j];
            float hi = W[(size_t)(kc + 2 * q + 1) * H + j];
            U.h2[q] = __floats2half2_rn(lo, hi);
        }
        *(uint4*)(wt + (size_t)j * WT_STRIDE + kc) = U.u;
    }
}

#define F4SCALE(a, s) { (a).x *= (s); (a).y *= (s); (a).z *= (s); (a).w *= (s); }
#define F4FMA(a, e, v) { (a).x += (e)*(v).x; (a).y += (e)*(v).y; (a).z += (e)*(v).z; (a).w += (e)*(v).w; }
#define F4DPPADD8(a) { (a).x += dpp_xor_f<DPP_XOR8>((a).x); (a).y += dpp_xor_f<DPP_XOR8>((a).y); \
                       (a).z += dpp_xor_f<DPP_XOR8>((a).z); (a).w += dpp_xor_f<DPP_XOR8>((a).w); }
#define F4SHFLADD(a, msk) { (a).x += __shfl_xor((a).x, msk, 64); (a).y += __shfl_xor((a).y, msk, 64); \
                            (a).z += __shfl_xor((a).z, msk, 64); (a).w += __shfl_xor((a).w, msk, 64); }

// ---------------- K2: fused score + online softmax + aggregation (R11-verified, frozen) ----------------
// one wave per dst node; 8 groups x 8 lanes, 8 edges in flight, lane owns 16 feats.
// DPP for xor1/2/8 (LDS-pipe relief, verified −4us R10). b row stays FP32 (R8:
// b-quant absmax 0.0205 > 0.02, banned). 16-edge chunks REGRESSED +7us (R12);
// branchy prefetch REGRESSED +12us (R2); device barriers REGRESSED (R3) — all banned.
// The ~41us here is random-gather fabric service (~4.7 TB/s aggregate) — at floor.
__global__ __launch_bounds__(256) void k_fused(const float* __restrict__ emb,
                                               const __half* __restrict__ emb16,
                                               const int* __restrict__ cnt,
                                               const ushort_t* __restrict__ slots,
                                               __half* __restrict__ neigh) {
    int wid = (blockIdx.x * blockDim.x + threadIdx.x) >> 6;
    int lane = threadIdx.x & 63;
    if (wid >= N_NODES) return;
    int g = lane >> 3;   // edge slot within chunk
    int l = lane & 7;    // feature slice: [16l, 16l+16)

    int deg = min(cnt[wid * CNT_STRIDE], MAXDEG);
    int sid = slots[wid * MAXDEG + min(lane, MAXDEG - 1)];

    const float4* rd = (const float4*)(emb + (size_t)wid * H) + l * 4;
    float4 b0 = rd[0], b1 = rd[1], b2 = rd[2], b3 = rd[3];

    float m = -INFINITY, ssum = 0.0f;
    float4 acc0 = {0,0,0,0}, acc1 = {0,0,0,0}, acc2 = {0,0,0,0}, acc3 = {0,0,0,0};

    for (int cb = 0; cb < deg; cb += 8) {
        int e = cb + g;
        bool valid = e < deg;
        int s = __shfl(sid, valid ? e : 0, 64);
        const uint4* rs = (const uint4*)(emb16 + (size_t)s * H) + l * 2;
        uint4 p0 = rs[0], p1 = rs[1];          // 16 halfs = feats [16l, 16l+16)
        const __half2* h0 = (const __half2*)&p0;
        const __half2* h1 = (const __half2*)&p1;
        float2 t0 = __half22float2(h0[0]), t1 = __half22float2(h0[1]);
        float2 t2 = __half22float2(h0[2]), t3 = __half22float2(h0[3]);
        float2 t4 = __half22float2(h1[0]), t5 = __half22float2(h1[1]);
        float2 t6 = __half22float2(h1[2]), t7 = __half22float2(h1[3]);
        float4 a0 = make_float4(t0.x, t0.y, t1.x, t1.y);
        float4 a1 = make_float4(t2.x, t2.y, t3.x, t3.y);
        float4 a2 = make_float4(t4.x, t4.y, t5.x, t5.y);
        float4 a3 = make_float4(t6.x, t6.y, t7.x, t7.y);

        float v = a0.x*b0.x + a0.y*b0.y + a0.z*b0.z + a0.w*b0.w
                + a1.x*b1.x + a1.y*b1.y + a1.z*b1.z + a1.w*b1.w
                + a2.x*b2.x + a2.y*b2.y + a2.z*b2.z + a2.w*b2.w
                + a3.x*b3.x + a3.y*b3.y + a3.z*b3.z + a3.w*b3.w;
        v += dpp_xor_f<DPP_XOR1>(v);          // xor1 (VALU)
        v += dpp_xor_f<DPP_XOR2>(v);          // xor2 (VALU)
        v += __shfl_xor(v, 4, 64);            // xor4 (LDS)
        if (!valid) v = -INFINITY;

        float cmax = v;
        cmax = fmaxf(cmax, dpp_xor_f<DPP_XOR8>(cmax));   // xor8 (VALU)
        cmax = fmaxf(cmax, __shfl_xor(cmax, 16, 64));
        cmax = fmaxf(cmax, __shfl_xor(cmax, 32, 64));
        float mnew = fmaxf(m, cmax);          // slot 0 always valid -> finite
        if (mnew > m) {                       // wave-uniform; skip is bit-identical
            float scale = __expf(m - mnew);   // first chunk: exp(-inf)=0
            ssum *= scale;
            F4SCALE(acc0, scale); F4SCALE(acc1, scale);
            F4SCALE(acc2, scale); F4SCALE(acc3, scale);
            m = mnew;
        }

        float ev = __expf(v - m);             // invalid: exp(-inf)=0
        ssum += ev;
        F4FMA(acc0, ev, a0); F4FMA(acc1, ev, a1);
        F4FMA(acc2, ev, a2); F4FMA(acc3, ev, a3);
    }

    // reduce across the 8 groups: xor8 via DPP (VALU), xor16/32 via LDS
    ssum += dpp_xor_f<DPP_XOR8>(ssum);
    ssum += __shfl_xor(ssum, 16, 64);
    ssum += __shfl_xor(ssum, 32, 64);
    F4DPPADD8(acc0);     F4DPPADD8(acc1);     F4DPPADD8(acc2);     F4DPPADD8(acc3);
    F4SHFLADD(acc0, 16); F4SHFLADD(acc1, 16); F4SHFLADD(acc2, 16); F4SHFLADD(acc3, 16);
    F4SHFLADD(acc0, 32); F4SHFLADD(acc1, 32); F4SHFLADD(acc2, 32); F4SHFLADD(acc3, 32);

    float inv = (deg > 0) ? 1.0f / ssum : 0.0f;
    if (g == 0) {
        F4SCALE(acc0, inv); F4SCALE(acc1, inv); F4SCALE(acc2, inv); F4SCALE(acc3, inv);
        union { uint4 u; __half2 h2[4]; } U0, U1;
        U0.h2[0] = __floats2half2_rn(acc0.x, acc0.y);
        U0.h2[1] = __floats2half2_rn(acc0.z, acc0.w);
        U0.h2[2] = __floats2half2_rn(acc1.x, acc1.y);
        U0.h2[3] = __floats2half2_rn(acc1.z, acc1.w);
        U1.h2[0] = __floats2half2_rn(acc2.x, acc2.y);
        U1.h2[1] = __floats2half2_rn(acc2.z, acc2.w);
        U1.h2[2] = __floats2half2_rn(acc3.x, acc3.y);
        U1.h2[3] = __floats2half2_rn(acc3.z, acc3.w);
        uint4* po = (uint4*)(neigh + (size_t)wid * H);
        po[2 * l] = U0.u;
        po[2 * l + 1] = U1.u;
    }
}

// ---------------- K3 v4: MFMA matmul h = neigh(fp16) @ W(fp16) + fused BN stats (verified R11) ----------------
// mfma_f32_16x16x32_f16, 4 waves/block x 16 rows x 128 cols. C/D col=lane&15,
// row=(lane>>4)*4+reg [m89/m91]; A/B element i at k=(i&3)+16*(i>>2)+(lane>>4)*4.
// B from LDS Wt[j][k] stride 136 (2-way bank alias = free). absmax-verified.
#define MM_ROWS 64
__global__ __launch_bounds__(256, 4) void k_matmul(const __half* __restrict__ neigh,
                                                   const __half* __restrict__ wt,
                                                   __half* __restrict__ hout,
                                                   float* __restrict__ stats) {
    __shared__ __half Wl[H * WT_STRIDE];   // 34816 B; stats scratch aliased after MFMAs
    int t = threadIdx.x;
    int wv = t >> 6;
    int l  = t & 63;
    int r0 = blockIdx.x * MM_ROWS + wv * 16;

    for (int idx = t; idx < H * WT_STRIDE / 8; idx += 256)
        ((uint4*)Wl)[idx] = ((const uint4*)wt)[idx];

    int rowA = r0 + (l & 15);
    if (rowA >= N_NODES) rowA = 0;
    const __half* pa = neigh + (size_t)rowA * H + ((l >> 4) * 4);

    __syncthreads();   // Wl staged

    f32x4 acc[8] = {};
#pragma unroll
    for (int kk = 0; kk < 4; ++kk) {
        uint2 a_lo = *(const uint2*)(pa + kk * 32);
        uint2 a_hi = *(const uint2*)(pa + kk * 32 + 16);
        uint4 au = make_uint4(a_lo.x, a_lo.y, a_hi.x, a_hi.y);
        f16x8 af = __builtin_bit_cast(f16x8, au);
#pragma unroll
        for (int jt = 0; jt < 8; ++jt) {
            const __half* pb = Wl + (size_t)(jt * 16 + (l & 15)) * WT_STRIDE
                             + kk * 32 + ((l >> 4) * 4);
            uint2 b_lo = *(const uint2*)(pb);
            uint2 b_hi = *(const uint2*)(pb + 16);
            uint4 bu = make_uint4(b_lo.x, b_lo.y, b_hi.x, b_hi.y);
            f16x8 bf = __builtin_bit_cast(f16x8, bu);
            acc[jt] = __builtin_amdgcn_mfma_f32_16x16x32_f16(af, bf, acc[jt], 0, 0, 0);
        }
    }

    int rbase = r0 + (l >> 4) * 4;
#pragma unroll
    for (int jt = 0; jt < 8; ++jt) {
        int col = jt * 16 + (l & 15);
#pragma unroll
        for (int reg = 0; reg < 4; ++reg) {
            int row = rbase + reg;
            if (row < N_NODES)
                hout[(size_t)row * H + col] = __float2half(acc[jt][reg]);
        }
    }

    // ---- BN column stats (fp32 from registers), scratch aliased into dead Wl ----
    __syncthreads();                   // all Wl (B) reads done before aliasing
    float* Sl = (float*)Wl;            // 16 x 128 = 8 KB
    float* Ql = Sl + 16 * H;           // next 8 KB
    int srow = wv * 4 + (l >> 4);
#pragma unroll
    for (int jt = 0; jt < 8; ++jt) {
        int col = jt * 16 + (l & 15);
        float s = 0.0f, q = 0.0f;
#pragma unroll
        for (int reg = 0; reg < 4; ++reg) {
            if (rbase + reg < N_NODES) { float v = acc[jt][reg]; s += v; q += v * v; }
        }
        Sl[srow * H + col] = s;
        Ql[srow * H + col] = q;
    }
    __syncthreads();
    if (t < H) {
        float s = 0.0f;
#pragma unroll
        for (int r = 0; r < 16; ++r) s += Sl[r * H + t];
        atomicAdd(stats + t, s);
    } else {
        int j = t - H;
        float q = 0.0f;
#pragma unroll
        for (int r = 0; r < 16; ++r) q += Ql[r * H + j];
        atomicAdd(stats + 128 + j, q);
    }
}

// fast tanh via v_exp: 1 - 2/(exp(2x)+1); saturates correctly at +/-inf
__device__ __forceinline__ float tanh_fast(float x) {
    float e = __expf(2.0f * x);
    return 1.0f - 2.0f / (e + 1.0f);
}

// ---------------- K4: finalize BN (in LDS) + apply + tanh; fp16 h -> fp32 out ----------------
__global__ __launch_bounds__(256) void k_apply_f16(const __half* __restrict__ h,
                                                   float* __restrict__ out,
                                                   const float* __restrict__ stats,
                                                   const float* __restrict__ gamma,
                                                   const float* __restrict__ beta) {
    __shared__ float sc[128], sh[128];
    int t = threadIdx.x;
    if (t < 128) {
        float mean = stats[t] * (1.0f / N_NODES);
        float var = stats[128 + t] * (1.0f / N_NODES) - mean * mean;
        var = fmaxf(var, 0.0f);
        float s = gamma[t] * rsqrtf(var + BN_EPS);
        sc[t] = s;
        sh[t] = beta[t] - mean * s;
    }
    __syncthreads();
    int i = blockIdx.x * 256 + t;                  // 8-half chunk index
    if (i < N_NODES * H / 8) {
        union { uint4 u; __half2 h2[4]; } U;
        U.u = ((const uint4*)h)[i];                // halfs [8i, 8i+8)
        int jb = (i & 15) * 8;                     // column of first half
        float2 f0 = __half22float2(U.h2[0]);
        float2 f1 = __half22float2(U.h2[1]);
        float2 f2 = __half22float2(U.h2[2]);
        float2 f3 = __half22float2(U.h2[3]);
        float4 o0, o1;
        o0.x = tanh_fast(f0.x * sc[jb]     + sh[jb]);
        o0.y = tanh_fast(f0.y * sc[jb + 1] + sh[jb + 1]);
        o0.z = tanh_fast(f1.x * sc[jb + 2] + sh[jb + 2]);
        o0.w = tanh_fast(f1.y * sc[jb + 3] + sh[jb + 3]);
        o1.x = tanh_fast(f2.x * sc[jb + 4] + sh[jb + 4]);
        o1.y = tanh_fast(f2.y * sc[jb + 5] + sh[jb + 5]);
        o1.z = tanh_fast(f3.x * sc[jb + 6] + sh[jb + 6]);
        o1.w = tanh_fast(f3.y * sc[jb + 7] + sh[jb + 7]);
        ((float4*)out)[2 * i]     = o0;
        ((float4*)out)[2 * i + 1] = o1;
    }
}

extern "C" void kernel_launch(void* const* d_in, const int* in_sizes, int n_in,
                              void* d_out, int out_size, void* d_ws, size_t ws_size,
                              hipStream_t stream) {
    const float* emb   = (const float*)d_in[0];
    const float* W     = (const float*)d_in[1];
    const float* gamma = (const float*)d_in[2];
    const float* beta  = (const float*)d_in[3];
    const int*   src   = (const int*)d_in[4];
    const int*   dst   = (const int*)d_in[5];
    float* out = (float*)d_out;

    // workspace: [cnt N*16][stats 256][pad 4][slots16 N*MAXDEG u16]
    //            [neigh16 N*H][hbuf16 N*H][emb16 N*H][wt 128*136 halfs] ~46.5 MB
    int*      cnt   = (int*)d_ws;                                    // N*CNT_STRIDE
    float*    stats = (float*)(cnt + (size_t)N_NODES * CNT_STRIDE);  // 256
    ushort_t* slots = (ushort_t*)((int*)(stats + 256) + 4);          // N*MAXDEG u16
    __half*   neigh = (__half*)(slots + (size_t)N_NODES * MAXDEG);   // N*H fp16
    __half*   hbuf  = neigh + (size_t)N_NODES * H;                   // N*H fp16
    __half*   emb16 = hbuf + (size_t)N_NODES * H;                    // N*H fp16
    __half*   wt    = emb16 + (size_t)N_NODES * H;                   // H*WT_STRIDE halfs

    // one memset zeroes padded cnt + stats + pad (contiguous, async)
    hipMemsetAsync(cnt, 0, ((size_t)N_NODES * CNT_STRIDE + 260) * sizeof(int), stream);
    int nthr_sc = N_NODES * H / 8;                 // 800000 >= 150000 edge-quads
    k_scatter<<<(nthr_sc + 255) / 256, 256, 0, stream>>>(src, dst, cnt, slots, emb, emb16, W, wt);
    k_fused<<<(N_NODES * 64 + 255) / 256, 256, 0, stream>>>(emb, emb16, cnt, slots, neigh);
    int nblk_mm = (N_NODES + MM_ROWS - 1) / MM_ROWS;   // 782
    k_matmul<<<nblk_mm, 256, 0, stream>>>(neigh, wt, hbuf, stats);
    k_apply_f16<<<(N_NODES * H / 8 + 255) / 256, 256, 0, stream>>>(hbuf, out, stats, gamma, beta);
}